// Round 1
// baseline (238.732 us; speedup 1.0000x reference)
//
#include <hip/hip_runtime.h>

// QRDQN n-step TD error. B=16384, N=32, TAU=64, NSTEP=5, gamma=0.99.
// out[0] = loss, out[1..B] = td_err_per_sample.
//
// R6: eliminate ALL d_ws usage. The previous structure staged per-block
// partials in d_ws, which pulled the harness's 512 MiB workspace poison
// fills (3 x ~79 us = ~237 us) into the timed region -- they were the
// entire measured cost (our kernels never appeared in the rocprof top-5).
// Now: kernel 1 writes only out[1..B] (pure per-wave, no block reduce,
// no __syncthreads); kernel 2 (one 1024-thread block) re-reads the
// freshly-written td values (L2-resident) plus weight and produces
// out[0] = dot(td, weight)/B deterministically.
//
// Kernel-1 inner loop kept from R5: float2 ext-vectors +
// __builtin_elementwise_fma so the backend selects v_pk_add_f32 /
// v_pk_fma_f32; med3 clamps stay scalar (no packed med3).

#define B_TOTAL 16384
#define N_ACT 32
#define TAU 64
#define NSTEP 5
#define GAMMA 0.99f
#define WPB 4                       // waves per block
#define NBLOCKS (B_TOTAL / WPB)     // 4096

typedef float v2f __attribute__((ext_vector_type(2)));

__global__ __launch_bounds__(256) void qrdqn_td_kernel(
    const float* __restrict__ q,
    const float* __restrict__ next_n_q,
    const int*   __restrict__ action,
    const int*   __restrict__ next_n_action,
    const float* __restrict__ reward,
    const float* __restrict__ done,
    float* __restrict__ out_td)      // d_out + 1 (B entries)
{
    const int lane = threadIdx.x & 63;
    const int wave = threadIdx.x >> 6;
    int b = blockIdx.x * WPB + wave;
    b = __builtin_amdgcn_readfirstlane(b);   // force s_load preamble

    const int   act  = action[b];
    const int   nact = next_n_action[b];
    const float dn   = done[b];

    float r = 0.0f, g = 1.0f;
    #pragma unroll
    for (int i = 0; i < NSTEP; ++i) {
        r += g * reward[i * B_TOTAL + b];
        g *= GAMMA;
    }
    const float vg = g * (1.0f - dn);        // gamma^nstep * (1-done)

    // coalesced row gathers: 64 lanes read 64 consecutive floats
    const float qi = q[((size_t)b * N_ACT + act) * TAU + lane];
    const float tq = next_n_q[((size_t)b * N_ACT + nact) * TAU + lane];
    const float tgt = fmaf(vg, tq, r);       // target quantile (lane = j)

    // wave-private LDS row; same-wave RAW -> compiler lgkmcnt, no barrier
    __shared__ float sm_t[WPB][TAU];
    sm_t[wave][lane] = tgt;

    const v2f nqi2  = (v2f)(-qi);
    const v2f half2 = (v2f)(-0.5f);
    v2f aP0 = (v2f)(0.0f), aP1 = (v2f)(0.0f);
    v2f aN0 = (v2f)(0.0f), aN1 = (v2f)(0.0f);
    const float4* trow = (const float4*)sm_t[wave];
    #pragma unroll
    for (int j4 = 0; j4 < TAU / 4; ++j4) {
        const float4 t4 = trow[j4];          // ds_read_b128, uniform addr
        const v2f u01 = (v2f){t4.x, t4.y} + nqi2;   // v_pk_add_f32
        const v2f u23 = (v2f){t4.z, t4.w} + nqi2;
        // clamp(u,0,1) / clamp(-u,0,1): scalar v_med3_f32
        const v2f mp01 = (v2f){__builtin_amdgcn_fmed3f(u01.x, 0.0f, 1.0f),
                               __builtin_amdgcn_fmed3f(u01.y, 0.0f, 1.0f)};
        const v2f mp23 = (v2f){__builtin_amdgcn_fmed3f(u23.x, 0.0f, 1.0f),
                               __builtin_amdgcn_fmed3f(u23.y, 0.0f, 1.0f)};
        const v2f mn01 = (v2f){__builtin_amdgcn_fmed3f(-u01.x, 0.0f, 1.0f),
                               __builtin_amdgcn_fmed3f(-u01.y, 0.0f, 1.0f)};
        const v2f mn23 = (v2f){__builtin_amdgcn_fmed3f(-u23.x, 0.0f, 1.0f),
                               __builtin_amdgcn_fmed3f(-u23.y, 0.0f, 1.0f)};
        // huber halves: m*(u_signed - 0.5m), pk_fma pairs
        aP0 = __builtin_elementwise_fma(mp01, __builtin_elementwise_fma(half2, mp01, u01), aP0);
        aP1 = __builtin_elementwise_fma(mp23, __builtin_elementwise_fma(half2, mp23, u23), aP1);
        aN0 = __builtin_elementwise_fma(mn01, __builtin_elementwise_fma(half2, mn01, -u01), aN0);
        aN1 = __builtin_elementwise_fma(mn23, __builtin_elementwise_fma(half2, mn23, -u23), aN1);
    }
    const v2f aP = aP0 + aP1, aN = aN0 + aN1;
    const float accP = aP.x + aP.y;
    const float accN = aN.x + aN.y;
    const float tau_i = ((float)lane + 0.5f) * (1.0f / (float)TAU);
    float val = fmaf(tau_i, accP - accN, accN);  // tau_i*accP + (1-tau_i)*accN

    // sum over lanes (= sum over i); mean over i via 1/TAU
    #pragma unroll
    for (int off = 32; off > 0; off >>= 1)
        val += __shfl_xor(val, off, 64);

    if (lane == 0)
        out_td[b] = val * (1.0f / (float)TAU);
}

// One 1024-thread block: loss = dot(td, weight) / B.
// td = out+1 is only 4-byte aligned -> scalar loads (fully coalesced,
// mostly L2 hits since kernel 1 just wrote them). 16 loads/thread/array.
__global__ __launch_bounds__(1024) void qrdqn_loss_kernel(
    const float* __restrict__ td,      // d_out + 1
    const float* __restrict__ weight,
    float* __restrict__ out_loss)      // d_out
{
    float s = 0.0f;
    #pragma unroll
    for (int k = 0; k < B_TOTAL / 1024; ++k) {   // 16 iters
        const int i = k * 1024 + threadIdx.x;
        s = fmaf(td[i], weight[i], s);
    }
    #pragma unroll
    for (int off = 32; off > 0; off >>= 1)
        s += __shfl_xor(s, off, 64);
    __shared__ float sr[16];
    const int wave = threadIdx.x >> 6;
    if ((threadIdx.x & 63) == 0) sr[wave] = s;
    __syncthreads();
    if (threadIdx.x < 16) {
        float v = sr[threadIdx.x];
        #pragma unroll
        for (int off = 8; off > 0; off >>= 1)
            v += __shfl_xor(v, off, 16);
        if (threadIdx.x == 0)
            out_loss[0] = v * (1.0f / (float)B_TOTAL);
    }
}

extern "C" void kernel_launch(void* const* d_in, const int* in_sizes, int n_in,
                              void* d_out, int out_size, void* d_ws, size_t ws_size,
                              hipStream_t stream)
{
    const float* q      = (const float*)d_in[0];
    const float* nq     = (const float*)d_in[1];
    const int*   act    = (const int*)d_in[2];
    const int*   nact   = (const int*)d_in[3];
    const float* reward = (const float*)d_in[4];
    const float* done   = (const float*)d_in[5];
    const float* weight = (const float*)d_in[6];
    float* out = (float*)d_out;

    (void)d_ws; (void)ws_size;   // deliberately unused: touching d_ws pulls
                                 // the 512 MiB workspace poison fills into
                                 // the timed region (~230 us)

    qrdqn_td_kernel<<<NBLOCKS, 256, 0, stream>>>(
        q, nq, act, nact, reward, done, out + 1);
    qrdqn_loss_kernel<<<1, 1024, 0, stream>>>(out + 1, weight, out);
}